// Round 1
// baseline (710.757 us; speedup 1.0000x reference)
//
#include <hip/hip_runtime.h>
#include <hip/hip_bf16.h>
#include <math.h>

// Problem constants (B, I, H) = (16384, 1024, 1024); K = I + H = 2048.
#define B_SZ 16384
#define H_SZ 1024
#define K_SZ 2048
#define OUT_PLANE ((size_t)B_SZ * H_SZ)   // 16777216

// Tile config: each block computes 128 b-rows x 32 h-cols x 4 gates
// (= 128x128 effective GEMM tile, m97-class instruction mix).
#define BM 128
#define BH 32
#define BK 64

typedef __bf16 bf16;
typedef __attribute__((ext_vector_type(8))) __bf16 bf16x8;
typedef __attribute__((ext_vector_type(4))) float floatx4;

__device__ __forceinline__ void gload_lds16(const bf16* g, bf16* l) {
    // async global->LDS, 16B per lane; LDS dest is wave-uniform base + lane*16
    __builtin_amdgcn_global_load_lds(
        (const __attribute__((address_space(1))) void*)g,
        (__attribute__((address_space(3))) void*)l, 16, 0, 0);
}

__device__ __forceinline__ float sigmoidf_fast(float x) {
    return 1.f / (1.f + __expf(-x));
}

// ---- cast fp32 -> bf16, packing [incoming | old_h] into X[b][0:2048] ----
__global__ void cvt_x(const float* __restrict__ inc, const float* __restrict__ oh,
                      bf16* __restrict__ X) {
    size_t t  = (size_t)blockIdx.x * blockDim.x + threadIdx.x;
    size_t e0 = t * 8;                 // 8 elems/thread, never straddles k=1024
    size_t b  = e0 >> 11;
    int    k  = (int)(e0 & 2047);
    const float* src = (k < 1024) ? (inc + b * 1024 + k)
                                  : (oh  + b * 1024 + (k - 1024));
    floatx4 f0 = *(const floatx4*)src;
    floatx4 f1 = *(const floatx4*)(src + 4);
    bf16x8 o;
    o[0]=(bf16)f0[0]; o[1]=(bf16)f0[1]; o[2]=(bf16)f0[2]; o[3]=(bf16)f0[3];
    o[4]=(bf16)f1[0]; o[5]=(bf16)f1[1]; o[6]=(bf16)f1[2]; o[7]=(bf16)f1[3];
    *(bf16x8*)(X + e0) = o;
}

// ---- cast fp32 -> bf16, packing [Wi | Wh] per (gate,h) row into W[n][0:2048] ----
// Wi flat index for row n=(g*1024+h): n*1024 + k  (same for Wh) — layouts line up.
__global__ void cvt_w(const float* __restrict__ Wi, const float* __restrict__ Wh,
                      bf16* __restrict__ W) {
    size_t t  = (size_t)blockIdx.x * blockDim.x + threadIdx.x;
    size_t e0 = t * 8;
    size_t n  = e0 >> 11;
    int    k  = (int)(e0 & 2047);
    const float* src = (k < 1024) ? (Wi + n * 1024 + k)
                                  : (Wh + n * 1024 + (k - 1024));
    floatx4 f0 = *(const floatx4*)src;
    floatx4 f1 = *(const floatx4*)(src + 4);
    bf16x8 o;
    o[0]=(bf16)f0[0]; o[1]=(bf16)f0[1]; o[2]=(bf16)f0[2]; o[3]=(bf16)f0[3];
    o[4]=(bf16)f1[0]; o[5]=(bf16)f1[1]; o[6]=(bf16)f1[2]; o[7]=(bf16)f1[3];
    *(bf16x8*)(W + e0) = o;
}

// ---- fused GEMM + LSTM epilogue ----
// grid = (H/BH, B/BM), block = 256 (4 waves). Wave wv owns b-rows
// [wv*32, wv*32+32) x 32 h-cols x 4 gates -> acc[4][2][2] floatx4 (64 regs).
__global__ __launch_bounds__(256, 2) void lstm_gemm(
    const bf16* __restrict__ X, const bf16* __restrict__ W,
    const float* __restrict__ bi, const float* __restrict__ oldc,
    float* __restrict__ out) {
    __shared__ bf16 As[BM * BK];      // [128 b-rows][64 k]
    __shared__ bf16 Bs[128 * BK];     // [g*32 + hoff][64 k]

    const int tid  = threadIdx.x;
    const int lane = tid & 63;
    const int wv   = tid >> 6;
    const int h0   = blockIdx.x * BH;
    const int brow0 = blockIdx.y * BM;

    floatx4 acc[4][2][2];
    #pragma unroll
    for (int g = 0; g < 4; ++g)
        #pragma unroll
        for (int n = 0; n < 2; ++n)
            #pragma unroll
            for (int m = 0; m < 2; ++m) {
                floatx4 z = {0.f, 0.f, 0.f, 0.f};
                acc[g][n][m] = z;
            }

    const int lrow = lane >> 3;        // 0..7: row within 8-row wave chunk
    const int lcol = (lane & 7) * 8;   // 0..56: k-element offset (16B each)

    const bf16* xg = X + (size_t)(brow0 + wv * 8 + lrow) * K_SZ + lcol;

    for (int kt = 0; kt < K_SZ; kt += BK) {
        // stage A tile: 4 rounds x (4 waves x 8 rows)
        #pragma unroll
        for (int r = 0; r < 4; ++r) {
            gload_lds16(xg + (size_t)(r * 32) * K_SZ + kt,
                        As + (r * 32 + wv * 8) * BK);
        }
        // stage B tile: row rb -> W row (rb>>5)*1024 + h0 + (rb&31)
        #pragma unroll
        for (int r = 0; r < 4; ++r) {
            int rb   = r * 32 + wv * 8 + lrow;
            int wrow = ((rb >> 5) << 10) + h0 + (rb & 31);
            gload_lds16(W + (size_t)wrow * K_SZ + kt + lcol,
                        Bs + (r * 32 + wv * 8) * BK);
        }
        __syncthreads();

        #pragma unroll
        for (int kk = 0; kk < BK; kk += 32) {
            const int arow = wv * 32 + (lane & 15);
            const int koff = kk + ((lane >> 4) << 3);
            bf16x8 a0 = *(const bf16x8*)(As + (size_t)(arow     ) * BK + koff);
            bf16x8 a1 = *(const bf16x8*)(As + (size_t)(arow + 16) * BK + koff);
            #pragma unroll
            for (int g = 0; g < 4; ++g) {
                #pragma unroll
                for (int n = 0; n < 2; ++n) {
                    bf16x8 bfr = *(const bf16x8*)(
                        Bs + (size_t)(g * 32 + n * 16 + (lane & 15)) * BK + koff);
                    acc[g][n][0] = __builtin_amdgcn_mfma_f32_16x16x32_bf16(
                        a0, bfr, acc[g][n][0], 0, 0, 0);
                    acc[g][n][1] = __builtin_amdgcn_mfma_f32_16x16x32_bf16(
                        a1, bfr, acc[g][n][1], 0, 0, 0);
                }
            }
        }
        __syncthreads();
    }

    // ---- fused epilogue: all 4 gates for (b,h) live in this lane ----
    float* outh  = out;
    float* outh2 = out + OUT_PLANE;
    float* outc  = out + 2 * OUT_PLANE;
    #pragma unroll
    for (int n = 0; n < 2; ++n) {
        const int h  = h0 + n * 16 + (lane & 15);
        const float b_i = bi[h];
        const float b_f = bi[H_SZ + h];
        const float b_g = bi[2 * H_SZ + h];
        const float b_o = bi[3 * H_SZ + h];
        #pragma unroll
        for (int m = 0; m < 2; ++m) {
            const int brow = brow0 + wv * 32 + m * 16 + ((lane >> 4) << 2);
            #pragma unroll
            for (int r = 0; r < 4; ++r) {
                const size_t idx = (size_t)(brow + r) * H_SZ + h;
                float gi = acc[0][n][m][r] + b_i;
                float gf = acc[1][n][m][r] + b_f;
                float gg = acc[2][n][m][r] + b_g;
                float go = acc[3][n][m][r] + b_o;
                float iv = sigmoidf_fast(gi);
                float fv = sigmoidf_fast(gf);
                float gv = tanhf(gg);
                float ov = sigmoidf_fast(go);
                float c  = fv * oldc[idx] + iv * gv;
                float hv = ov * tanhf(c);
                outh[idx]  = hv;
                outh2[idx] = hv;
                outc[idx]  = c;
            }
        }
    }
}

// ---- insurance fallback if d_ws is too small for the bf16 pack (slow, fp32) ----
__global__ void lstm_fallback(const float* __restrict__ X, const float* __restrict__ Ho,
                              const float* __restrict__ Co, const float* __restrict__ Wi,
                              const float* __restrict__ bi, const float* __restrict__ Wh,
                              float* __restrict__ out) {
    int b = blockIdx.x;
    __shared__ float xs[1024], hs[1024];
    for (int k = threadIdx.x; k < 1024; k += blockDim.x) {
        xs[k] = X[(size_t)b * 1024 + k];
        hs[k] = Ho[(size_t)b * 1024 + k];
    }
    __syncthreads();
    for (int h = threadIdx.x; h < 1024; h += blockDim.x) {
        float g[4];
        for (int gg = 0; gg < 4; ++gg) {
            const float* wi = Wi + ((size_t)gg * 1024 + h) * 1024;
            const float* wh = Wh + ((size_t)gg * 1024 + h) * 1024;
            float acc = bi[gg * 1024 + h];
            for (int k = 0; k < 1024; ++k) acc += xs[k] * wi[k] + hs[k] * wh[k];
            g[gg] = acc;
        }
        float iv = sigmoidf_fast(g[0]);
        float fv = sigmoidf_fast(g[1]);
        float gv = tanhf(g[2]);
        float ov = sigmoidf_fast(g[3]);
        float c  = fv * Co[(size_t)b * 1024 + h] + iv * gv;
        float hv = ov * tanhf(c);
        size_t idx = (size_t)b * 1024 + h;
        out[idx] = hv;
        out[OUT_PLANE + idx] = hv;
        out[2 * OUT_PLANE + idx] = c;
    }
}

extern "C" void kernel_launch(void* const* d_in, const int* in_sizes, int n_in,
                              void* d_out, int out_size, void* d_ws, size_t ws_size,
                              hipStream_t stream) {
    const float* incoming = (const float*)d_in[0];
    const float* old_h    = (const float*)d_in[1];
    const float* old_c    = (const float*)d_in[2];
    const float* Wi       = (const float*)d_in[3];
    const float* bi       = (const float*)d_in[4];
    const float* Wh       = (const float*)d_in[5];
    float* out = (float*)d_out;

    const size_t nX = (size_t)B_SZ * K_SZ;       // bf16 elems
    const size_t nW = (size_t)4 * H_SZ * K_SZ;   // bf16 elems
    if (ws_size < (nX + nW) * sizeof(bf16)) {
        lstm_fallback<<<B_SZ, 256, 0, stream>>>(incoming, old_h, old_c, Wi, bi, Wh, out);
        return;
    }
    bf16* X = (bf16*)d_ws;
    bf16* W = X + nX;

    cvt_x<<<(int)(nX / 8 / 256), 256, 0, stream>>>(incoming, old_h, X);
    cvt_w<<<(int)(nW / 8 / 256), 256, 0, stream>>>(Wi, Wh, W);

    dim3 grid(H_SZ / BH, B_SZ / BM);   // (32, 128) = 4096 blocks
    lstm_gemm<<<grid, 256, 0, stream>>>(X, W, bi, old_c, out);
}

// Round 2
// 613.737 us; speedup vs baseline: 1.1581x; 1.1581x over previous
//
#include <hip/hip_runtime.h>
#include <hip/hip_bf16.h>
#include <math.h>

// Problem constants (B, I, H) = (16384, 1024, 1024); K = I + H = 2048.
#define B_SZ 16384
#define H_SZ 1024
#define K_SZ 2048
#define OUT_PLANE ((size_t)B_SZ * H_SZ)   // 16777216

// Tile config: each block computes 128 b-rows x 32 h-cols x 4 gates
// (= 128x128 effective GEMM tile).
#define BM 128
#define BH 32
#define BK 64

typedef __bf16 bf16;
typedef __attribute__((ext_vector_type(8))) __bf16 bf16x8;
typedef __attribute__((ext_vector_type(4))) float floatx4;

__device__ __forceinline__ void gload_lds16(const bf16* g, bf16* l) {
    // async global->LDS, 16B per lane; LDS dest is wave-uniform base + lane*16
    __builtin_amdgcn_global_load_lds(
        (const __attribute__((address_space(1))) void*)g,
        (__attribute__((address_space(3))) void*)l, 16, 0, 0);
}

__device__ __forceinline__ float sigmoidf_fast(float x) {
    return 1.f / (1.f + __expf(-x));
}
__device__ __forceinline__ float tanhf_fast(float x) {
    // tanh(x) = 2*sigmoid(2x) - 1 ; accuracy ~1e-7 rel, far below bf16 tol
    return 2.f / (1.f + __expf(-2.f * x)) - 1.f;
}

// ---- fused fp32->bf16 pack: X = [incoming | old_h] (B x 2048),
//      W = [Wi | Wh] per (gate,h) row (4096 x 2048) ----
__global__ void cvt_all(const float* __restrict__ inc, const float* __restrict__ oh,
                        const float* __restrict__ Wi, const float* __restrict__ Wh,
                        bf16* __restrict__ X, bf16* __restrict__ W) {
    const size_t nX = (size_t)B_SZ * K_SZ;
    size_t t  = (size_t)blockIdx.x * blockDim.x + threadIdx.x;
    size_t e0 = t * 8;                 // 8 elems/thread, never straddles k=1024
    const float* src;
    bf16* dst;
    if (e0 < nX) {
        size_t b = e0 >> 11;
        int    k = (int)(e0 & 2047);
        src = (k < 1024) ? (inc + b * 1024 + k) : (oh + b * 1024 + (k - 1024));
        dst = X + e0;
    } else {
        size_t e = e0 - nX;
        size_t n = e >> 11;
        int    k = (int)(e & 2047);
        src = (k < 1024) ? (Wi + n * 1024 + k) : (Wh + n * 1024 + (k - 1024));
        dst = W + e;
    }
    floatx4 f0 = *(const floatx4*)src;
    floatx4 f1 = *(const floatx4*)(src + 4);
    bf16x8 o;
    o[0]=(bf16)f0[0]; o[1]=(bf16)f0[1]; o[2]=(bf16)f0[2]; o[3]=(bf16)f0[3];
    o[4]=(bf16)f1[0]; o[5]=(bf16)f1[1]; o[6]=(bf16)f1[2]; o[7]=(bf16)f1[3];
    *(bf16x8*)dst = o;
}

// ---- fused GEMM + LSTM epilogue ----
// grid = (H/BH, B/BM), block = 256 (4 waves). Wave wv owns b-rows
// [wv*32, wv*32+32) x 32 h-cols x 4 gates -> acc[4][2][2] floatx4.
//
// LDS layout is XOR-swizzled to kill the 16-way bank conflicts of the naive
// 128B-row-stride layout: logical 16B chunk c of row r lives at chunk slot
// (c ^ (r&7)) within the row. Staging keeps the LDS destination contiguous
// (global_load_lds constraint) and permutes each lane's GLOBAL k-offset
// instead; 8 lanes still cover one 128B row segment -> coalescing intact.
__global__ __launch_bounds__(256, 4) void lstm_gemm(
    const bf16* __restrict__ X, const bf16* __restrict__ W,
    const float* __restrict__ bi, const float* __restrict__ oldc,
    float* __restrict__ out) {
    __shared__ bf16 As[BM * BK];      // [128 b-rows][64 k] (chunk-swizzled)
    __shared__ bf16 Bs[128 * BK];     // [g*32 + hoff][64 k] (chunk-swizzled)

    const int tid  = threadIdx.x;
    const int lane = tid & 63;
    const int wv   = tid >> 6;
    const int h0   = blockIdx.x * BH;
    const int brow0 = blockIdx.y * BM;

    floatx4 acc[4][2][2];
    #pragma unroll
    for (int g = 0; g < 4; ++g)
        #pragma unroll
        for (int n = 0; n < 2; ++n)
            #pragma unroll
            for (int m = 0; m < 2; ++m) {
                floatx4 z = {0.f, 0.f, 0.f, 0.f};
                acc[g][n][m] = z;
            }

    const int lrow = lane >> 3;                       // 0..7: row in wave chunk
    const int lcol = (((lane & 7) ^ lrow) * 8);       // swizzled global k-chunk

    const bf16* xg = X + (size_t)(brow0 + wv * 8 + lrow) * K_SZ + lcol;

    for (int kt = 0; kt < K_SZ; kt += BK) {
        // stage A tile: 4 rounds x (4 waves x 8 rows)
        #pragma unroll
        for (int r = 0; r < 4; ++r) {
            gload_lds16(xg + (size_t)(r * 32) * K_SZ + kt,
                        As + (r * 32 + wv * 8) * BK);
        }
        // stage B tile: LDS row rb <- W row (rb>>5)*1024 + h0 + (rb&31)
        #pragma unroll
        for (int r = 0; r < 4; ++r) {
            int rb   = r * 32 + wv * 8 + lrow;
            int wrow = ((rb >> 5) << 10) + h0 + (rb & 31);
            gload_lds16(W + (size_t)wrow * K_SZ + kt + lcol,
                        Bs + (r * 32 + wv * 8) * BK);
        }
        __syncthreads();

        #pragma unroll
        for (int kk = 0; kk < BK; kk += 32) {
            const int q    = lane >> 4;               // 0..3
            const int cidx = (kk >> 3) + q;           // logical 16B chunk 0..7
            const int arow0 = wv * 32 + (lane & 15);
            const int arow1 = arow0 + 16;
            bf16x8 a0 = *(const bf16x8*)(
                As + (size_t)arow0 * BK + ((cidx ^ (arow0 & 7)) * 8));
            bf16x8 a1 = *(const bf16x8*)(
                As + (size_t)arow1 * BK + ((cidx ^ (arow1 & 7)) * 8));
            #pragma unroll
            for (int g = 0; g < 4; ++g) {
                #pragma unroll
                for (int n = 0; n < 2; ++n) {
                    const int brow = g * 32 + n * 16 + (lane & 15);
                    bf16x8 bfr = *(const bf16x8*)(
                        Bs + (size_t)brow * BK + ((cidx ^ (brow & 7)) * 8));
                    acc[g][n][0] = __builtin_amdgcn_mfma_f32_16x16x32_bf16(
                        a0, bfr, acc[g][n][0], 0, 0, 0);
                    acc[g][n][1] = __builtin_amdgcn_mfma_f32_16x16x32_bf16(
                        a1, bfr, acc[g][n][1], 0, 0, 0);
                }
            }
        }
        __syncthreads();
    }

    // ---- fused epilogue: all 4 gates for (b,h) live in this lane ----
    float* outh  = out;
    float* outh2 = out + OUT_PLANE;
    float* outc  = out + 2 * OUT_PLANE;
    #pragma unroll
    for (int n = 0; n < 2; ++n) {
        const int h  = h0 + n * 16 + (lane & 15);
        const float b_i = bi[h];
        const float b_f = bi[H_SZ + h];
        const float b_g = bi[2 * H_SZ + h];
        const float b_o = bi[3 * H_SZ + h];
        #pragma unroll
        for (int m = 0; m < 2; ++m) {
            const int brow = brow0 + wv * 32 + m * 16 + ((lane >> 4) << 2);
            #pragma unroll
            for (int r = 0; r < 4; ++r) {
                const size_t idx = (size_t)(brow + r) * H_SZ + h;
                float gi = acc[0][n][m][r] + b_i;
                float gf = acc[1][n][m][r] + b_f;
                float gg = acc[2][n][m][r] + b_g;
                float go = acc[3][n][m][r] + b_o;
                float iv = sigmoidf_fast(gi);
                float fv = sigmoidf_fast(gf);
                float gv = tanhf_fast(gg);
                float ov = sigmoidf_fast(go);
                float c  = fv * oldc[idx] + iv * gv;
                float hv = ov * tanhf_fast(c);
                outh[idx]  = hv;
                outh2[idx] = hv;
                outc[idx]  = c;
            }
        }
    }
}

// ---- insurance fallback if d_ws is too small for the bf16 pack (slow, fp32) ----
__global__ void lstm_fallback(const float* __restrict__ X, const float* __restrict__ Ho,
                              const float* __restrict__ Co, const float* __restrict__ Wi,
                              const float* __restrict__ bi, const float* __restrict__ Wh,
                              float* __restrict__ out) {
    int b = blockIdx.x;
    __shared__ float xs[1024], hs[1024];
    for (int k = threadIdx.x; k < 1024; k += blockDim.x) {
        xs[k] = X[(size_t)b * 1024 + k];
        hs[k] = Ho[(size_t)b * 1024 + k];
    }
    __syncthreads();
    for (int h = threadIdx.x; h < 1024; h += blockDim.x) {
        float g[4];
        for (int gg = 0; gg < 4; ++gg) {
            const float* wi = Wi + ((size_t)gg * 1024 + h) * 1024;
            const float* wh = Wh + ((size_t)gg * 1024 + h) * 1024;
            float acc = bi[gg * 1024 + h];
        for (int k = 0; k < 1024; ++k) acc += xs[k] * wi[k] + hs[k] * wh[k];
            g[gg] = acc;
        }
        float iv = sigmoidf_fast(g[0]);
        float fv = sigmoidf_fast(g[1]);
        float gv = tanhf_fast(g[2]);
        float ov = sigmoidf_fast(g[3]);
        float c  = fv * Co[(size_t)b * 1024 + h] + iv * gv;
        float hv = ov * tanhf_fast(c);
        size_t idx = (size_t)b * 1024 + h;
        out[idx] = hv;
        out[OUT_PLANE + idx] = hv;
        out[2 * OUT_PLANE + idx] = c;
    }
}

extern "C" void kernel_launch(void* const* d_in, const int* in_sizes, int n_in,
                              void* d_out, int out_size, void* d_ws, size_t ws_size,
                              hipStream_t stream) {
    const float* incoming = (const float*)d_in[0];
    const float* old_h    = (const float*)d_in[1];
    const float* old_c    = (const float*)d_in[2];
    const float* Wi       = (const float*)d_in[3];
    const float* bi       = (const float*)d_in[4];
    const float* Wh       = (const float*)d_in[5];
    float* out = (float*)d_out;

    const size_t nX = (size_t)B_SZ * K_SZ;       // bf16 elems
    const size_t nW = (size_t)4 * H_SZ * K_SZ;   // bf16 elems
    if (ws_size < (nX + nW) * sizeof(bf16)) {
        lstm_fallback<<<B_SZ, 256, 0, stream>>>(incoming, old_h, old_c, Wi, bi, Wh, out);
        return;
    }
    bf16* X = (bf16*)d_ws;
    bf16* W = X + nX;

    const int cvt_blocks = (int)((nX + nW) / 8 / 256);   // 20480
    cvt_all<<<cvt_blocks, 256, 0, stream>>>(incoming, old_h, Wi, Wh, X, W);

    dim3 grid(H_SZ / BH, B_SZ / BM);   // (32, 128) = 4096 blocks
    lstm_gemm<<<grid, 256, 0, stream>>>(X, W, bi, old_c, out);
}